// Round 2
// baseline (226.241 us; speedup 1.0000x reference)
//
#include <hip/hip_runtime.h>
#include <hip/hip_bf16.h>

// GCN layer: out = relu( A0 @ (X W0) + A1 @ (X W1) + bias )
// N=50000, D=128, E=800000 per adjacency, fp32 in/out, COO edges.
//
// R15 (this round):
//   prep        W0/W1 -> bf16 transposed (8 blocks, k-split) + zero cur. (verbatim)
//   gemm_fused  R13-verbatim standalone (14.6 KB LDS -> 4 blocks/CU). R14's
//               fusion with fill shared a 70 KB LDS union -> 2 blocks/CU and
//               regressed the pair ~57us -> 71.9us. NEVER re-fuse these.
//   fill6       standalone: 512 thr / 4096 edges, wave-shuffle scan (5
//               barriers), int4/float4 edge loads, bstart/part dropped
//               (start[k] == lcur[k-1] post-scatter). 392 blocks, 2/CU.
//   aggregate10 = aggregate9 with srec removed (scatter pass re-reads recs
//               from global, L2/L3-hot): LDS 23->11.6 KB -> 8 blocks/CU
//               (was occupancy 50.5%, latency-bound at 3.3 TB/s gather).
//               Gather loop itself VERBATIM (measured pinned ~177MB FETCH).
// NEVER use fp32 LDS atomics in the per-record loop (R4: 1234us, R9: 1216us).
// NOTE: dur_us carries ~81us of fixed harness overhead (R13 vs R14 algebra);
//       compare kernel dispatch times, not totals, when judging changes.

#define BROWS 32                   // bucket = 32 dst rows
#define NBUCK 1563                 // ceil(50000/32)
#define NB2 2048                   // padded bin count
#define BCAP 704                   // records per (bucket,adj); mean 512, +8.5 sigma
#define ACAP (2 * BCAP)
#define FT6 4096                   // fill tile (edges per block) = 512 thr * 8
#define PREROWS 65536              // adj stride in unified pre

typedef __attribute__((ext_vector_type(8))) short bf16x8;
typedef __attribute__((ext_vector_type(4))) float f32x4;

__device__ inline unsigned short f2bf(float f) {
    union { float f; unsigned u; } v; v.f = f;
    unsigned r = v.u + 0x7fff + ((v.u >> 16) & 1);   // round-nearest-even
    return (unsigned short)(r >> 16);
}

// blocks 0..7: W transpose (4 k-slices x 2 Ws). block 8: zero cur.
__global__ __launch_bounds__(256) void prep_kernel(
    const float* __restrict__ W0, const float* __restrict__ W1,
    unsigned short* __restrict__ wt0, unsigned short* __restrict__ wt1,
    int* __restrict__ cur, int ncur)
{
    const int bid = blockIdx.x;
    const int tid = threadIdx.x;
    if (bid >= 8) {
        for (int i = tid; i < ncur; i += 256) cur[i] = 0;
        return;
    }
    const int which = bid >> 2;
    const int k0 = (bid & 3) * 32;
    const float* __restrict__ W = which ? W1 : W0;
    unsigned short* __restrict__ wt = which ? wt1 : wt0;
    for (int i = tid; i < 32 * 128; i += 256) {
        int k = k0 + (i >> 7), n = i & 127;
        wt[n * 128 + k] = f2bf(W[k * 128 + n]);
    }
}

// One block: 16 x-rows, BOTH adjacencies. Waves 0-3 -> W0 cols, 4-7 -> W1.
// Block stages x rows fp32->bf16 into LDS once; waves ds_read A-frags.
// (R13-verbatim: 14.6 KB LDS -> 4 blocks/CU.)
__global__ __launch_bounds__(512) void gemm_fused_kernel(
    const float* __restrict__ x,
    const unsigned short* __restrict__ wt0,
    const unsigned short* __restrict__ wt1,
    unsigned short* __restrict__ pre,    // unified: adj*PREROWS + row
    int N)
{
    __shared__ unsigned short sA[16][136];  // bf16 A-tile, pad: 272B row
    __shared__ short ctile[8][16][40];      // per-wave 16x32 C tile (+pad)

    const int tid = threadIdx.x;
    const int m0 = blockIdx.x * 16;

    // stage A: 512 float4 loads (1 per thread), convert, store 8B to LDS
    {
        int r = tid >> 5;                 // 32 float4 per row
        int c4 = (tid & 31) << 2;
        float4 v = *(const float4*)&x[(m0 + r) * 128 + c4];
        ushort4 s;
        s.x = f2bf(v.x); s.y = f2bf(v.y); s.z = f2bf(v.z); s.w = f2bf(v.w);
        *(ushort4*)&sA[r][c4] = s;
    }
    __syncthreads();

    const int w = tid >> 6;
    const int lane = tid & 63;
    const int adj = w >> 2;
    const int wq = w & 3;
    const unsigned short* __restrict__ wt = adj ? wt1 : wt0;
    unsigned short* __restrict__ po = pre + (size_t)adj * PREROWS * 128;
    const int l15 = lane & 15;
    const int quad = lane >> 4;
    const int nA = wq * 32 + l15;

    f32x4 c0 = {0.f, 0.f, 0.f, 0.f};
    f32x4 c1 = {0.f, 0.f, 0.f, 0.f};
#pragma unroll
    for (int k0 = 0; k0 < 128; k0 += 32) {
        union { bf16x8 v; ushort4 h[2]; } au;
        au.h[0] = *(const ushort4*)&sA[l15][k0 + quad * 8];
        au.h[1] = *(const ushort4*)&sA[l15][k0 + quad * 8 + 4];
        bf16x8 b0 = *(const bf16x8*)&wt[nA * 128 + k0 + quad * 8];
        bf16x8 b1 = *(const bf16x8*)&wt[(nA + 16) * 128 + k0 + quad * 8];
        c0 = __builtin_amdgcn_mfma_f32_16x16x32_bf16(au.v, b0, c0, 0, 0, 0);
        c1 = __builtin_amdgcn_mfma_f32_16x16x32_bf16(au.v, b1, c1, 0, 0, 0);
    }

    // stage C into wave-private LDS tile (wave-internal dep: no barrier)
#pragma unroll
    for (int i = 0; i < 4; ++i) {
        ctile[w][quad * 4 + i][l15]      = (short)f2bf(c0[i]);
        ctile[w][quad * 4 + i][16 + l15] = (short)f2bf(c1[i]);
    }
    const int rr = lane >> 2, cg = (lane & 3) * 8;
    ushort4 s0 = *(ushort4*)&ctile[w][rr][cg];
    ushort4 s1 = *(ushort4*)&ctile[w][rr][cg + 4];
    int row = m0 + rr;                        // N % 16 == 0, always < N
    *(ushort4*)&po[row * 128 + wq * 32 + cg] = s0;
    *(ushort4*)&po[row * 128 + wq * 32 + cg + 4] = s1;
}

// Standalone fill (logic verified in R14's mid_kernel): 512 thr / 4096 edges.
// Wave-shuffle scan, int4/float4 edge loads, start[k] == lcur[k-1] trick.
// grid (196, 2); ~69.9 KB LDS -> 2 blocks/CU, 392 blocks cover all 256 CUs.
__global__ __launch_bounds__(512) void fill6_kernel(
    const int* __restrict__ ei0, const int* __restrict__ ei1,
    const float* __restrict__ ev0, const float* __restrict__ ev1,
    int* __restrict__ cur, int2* __restrict__ recs, int E)
{
    __shared__ int2 srt[FT6];                 // 32 KB sorted records
    __shared__ alignas(16) int lcnt[NB2];     // 8 KB per-bucket counts
    __shared__ alignas(16) int lcur[NB2];     // 8 KB cursors (end == next start)
    __shared__ unsigned short skey[FT6];      // 8 KB bucket of each sorted record
    __shared__ int gpos[NBUCK];               // 6.25 KB global base per bucket
    __shared__ int glim[NBUCK];               // 6.25 KB
    __shared__ int wsum[8];
    __shared__ int stotal;

    const int tid = threadIdx.x;
    const int a = blockIdx.y;
    const int e0 = blockIdx.x * FT6;
    const int* __restrict__ ei = a ? ei1 : ei0;
    const float* __restrict__ ev = a ? ev1 : ev0;

    ((int4*)lcnt)[tid] = make_int4(0, 0, 0, 0);
    __syncthreads();

    // load 8 consecutive edges per thread (int4/float4 vector loads)
    const int eb = e0 + tid * 8;
    int dd[8], ss[8]; float vv[8];
    if (e0 + FT6 <= E) {
        int4 d0 = *(const int4*)(ei + eb);
        int4 d1 = *(const int4*)(ei + eb + 4);
        int4 s0 = *(const int4*)(ei + E + eb);
        int4 s1 = *(const int4*)(ei + E + eb + 4);
        float4 v0 = *(const float4*)(ev + eb);
        float4 v1 = *(const float4*)(ev + eb + 4);
        dd[0] = d0.x; dd[1] = d0.y; dd[2] = d0.z; dd[3] = d0.w;
        dd[4] = d1.x; dd[5] = d1.y; dd[6] = d1.z; dd[7] = d1.w;
        ss[0] = s0.x; ss[1] = s0.y; ss[2] = s0.z; ss[3] = s0.w;
        ss[4] = s1.x; ss[5] = s1.y; ss[6] = s1.z; ss[7] = s1.w;
        vv[0] = v0.x; vv[1] = v0.y; vv[2] = v0.z; vv[3] = v0.w;
        vv[4] = v1.x; vv[5] = v1.y; vv[6] = v1.z; vv[7] = v1.w;
    } else {
#pragma unroll
        for (int j = 0; j < 8; ++j) {
            int e = eb + j;
            if (e < E) { dd[j] = ei[e]; ss[j] = ei[E + e]; vv[j] = ev[e]; }
        }
    }
    int key8[8]; int2 rec[8];
#pragma unroll
    for (int j = 0; j < 8; ++j) {
        if (eb + j < E) {
            key8[j] = dd[j] >> 5;
            rec[j] = make_int2(((dd[j] & 31) << 17) | (a << 16) | ss[j],
                               __float_as_int(vv[j]));
            atomicAdd(&lcnt[key8[j]], 1);
        } else key8[j] = -1;
    }
    __syncthreads();

    // wave-shuffle exclusive scan over 2048 bins (4 per thread)
    const int lane = tid & 63;
    const int wv = tid >> 6;
    int4 c4 = ((const int4*)lcnt)[tid];
    int cc[4] = { c4.x, c4.y, c4.z, c4.w };
    int tsum = cc[0] + cc[1] + cc[2] + cc[3];
    int p = tsum;
#pragma unroll
    for (int o = 1; o < 64; o <<= 1) {
        int t = __shfl_up(p, o);
        if (lane >= o) p += t;
    }
    if (lane == 63) wsum[wv] = p;
    __syncthreads();
    int wbase = 0;
#pragma unroll
    for (int w2 = 0; w2 < 7; ++w2) wbase += (w2 < wv) ? wsum[w2] : 0;
    if (tid == 511) stotal = wbase + p;
    int off = wbase + p - tsum;          // exclusive start of bin 4*tid
    const int k0 = 4 * tid;
#pragma unroll
    for (int h = 0; h < 4; ++h) {
        lcur[k0 + h] = off;
        if (k0 + h < NBUCK && cc[h] > 0) {
            int bin = (k0 + h) * 2 + a;
            int g = atomicAdd(&cur[bin], cc[h]);
            int lim = BCAP - g; if (lim < 0) lim = 0;   // overflow guard
            gpos[k0 + h] = bin * BCAP + g;
            glim[k0 + h] = lim;
        }
        off += cc[h];
    }
    __syncthreads();

    // scatter into LDS sorted by bucket
#pragma unroll
    for (int j = 0; j < 8; ++j) {
        if (key8[j] >= 0) {
            int pp = atomicAdd(&lcur[key8[j]], 1);
            srt[pp] = rec[j];
            skey[pp] = (unsigned short)key8[j];
        }
    }
    __syncthreads();

    // coalesced write-out; start[k] == lcur[k-1] (ends are next starts)
    const int total = stotal;
    for (int i = tid; i < total; i += 512) {
        int k = skey[i];
        int st = k ? lcur[k - 1] : 0;
        int r = i - st;
        if (r < glim[k]) recs[gpos[k] + r] = srt[i];
    }
}

// One block per 32-row bucket (256 thr = 4 waves, wave wv -> rows wv*8..+7).
// R15: srec dropped -- count pass and scatter pass both read recs from global
// (L2/L3-hot, ~13MB extra). LDS 23 -> 11.6 KB => 8 blocks/CU (32 waves).
// Gather loop + sort structure VERBATIM from aggregate9 (measured pinned).
__global__ __launch_bounds__(256, 8) void aggregate10_kernel(
    const int* __restrict__ cur, const int2* __restrict__ recs,
    const unsigned short* __restrict__ pre,
    const float* __restrict__ bias,
    float* __restrict__ out, int N)
{
    __shared__ int2 srt[ACAP];              // 11.3 KB row-sorted
    __shared__ int lcnt[32];
    __shared__ int lstart[32];
    __shared__ int lcur[32];

    const int b = blockIdx.x;
    const int tid = threadIdx.x;

    int n0 = cur[2 * b];     if (n0 > BCAP) n0 = BCAP;
    int n1 = cur[2 * b + 1]; if (n1 > BCAP) n1 = BCAP;
    const int total = n0 + n1;
    const int base0 = (2 * b) * BCAP, base1 = (2 * b + 1) * BCAP;

    if (tid < 32) lcnt[tid] = 0;
    __syncthreads();

    // pass 1: per-row counts (int LDS atomics)
    for (int i = tid; i < total; i += 256) {
        int2 r = (i < n0) ? recs[base0 + i] : recs[base1 + i - n0];
        atomicAdd(&lcnt[(r.x >> 17) & 31], 1);
    }
    __syncthreads();

    // wave 0 lanes 0-31: shfl exclusive scan of 32 counters
    if (tid < 32) {
        int cme = lcnt[tid];
        int p = cme;
#pragma unroll
        for (int o = 1; o < 32; o <<= 1) {
            int t = __shfl_up(p, o);
            if (tid >= o) p += t;
        }
        lstart[tid] = p - cme;
        lcur[tid] = p - cme;
    }
    __syncthreads();

    // pass 2: re-read recs, scatter full records sorted by row
    for (int i = tid; i < total; i += 256) {
        int2 r = (i < n0) ? recs[base0 + i] : recs[base1 + i - n0];
        srt[atomicAdd(&lcur[(r.x >> 17) & 31], 1)] = r;
    }
    __syncthreads();

    // gather: wave wv owns rows wv*8 .. wv*8+7; both adjacencies in one run
    const int wv = tid >> 6;
    const int lane = tid & 63;
    const float2 bi = *(const float2*)&bias[lane * 2];

#define GA(r) (*(const unsigned*)&pre[((r).x & 0x1ffff) * 128 + 2 * lane])
#define ACC(r, u) { float v = __int_as_float((r).y);                    \
        acc.x = fmaf(v, __uint_as_float((u) << 16), acc.x);             \
        acc.y = fmaf(v, __uint_as_float((u) & 0xffff0000u), acc.y); }

    for (int t = 0; t < 8; ++t) {
        const int rl = wv * 8 + t;
        const int s = lstart[rl];
        const int e = s + lcnt[rl];
        float2 acc = make_float2(0.f, 0.f);
        int j = s;
        for (; j + 8 <= e; j += 8) {
            int2 r0 = srt[j], r1 = srt[j + 1], r2 = srt[j + 2], r3 = srt[j + 3];
            int2 r4 = srt[j + 4], r5 = srt[j + 5], r6 = srt[j + 6], r7 = srt[j + 7];
            unsigned u0 = GA(r0), u1 = GA(r1), u2 = GA(r2), u3 = GA(r3);
            unsigned u4 = GA(r4), u5 = GA(r5), u6 = GA(r6), u7 = GA(r7);
            ACC(r0, u0); ACC(r1, u1); ACC(r2, u2); ACC(r3, u3);
            ACC(r4, u4); ACC(r5, u5); ACC(r6, u6); ACC(r7, u7);
        }
        for (; j + 4 <= e; j += 4) {
            int2 r0 = srt[j], r1 = srt[j + 1], r2 = srt[j + 2], r3 = srt[j + 3];
            unsigned u0 = GA(r0), u1 = GA(r1), u2 = GA(r2), u3 = GA(r3);
            ACC(r0, u0); ACC(r1, u1); ACC(r2, u2); ACC(r3, u3);
        }
        for (; j < e; ++j) {
            int2 r0 = srt[j];
            unsigned u0 = GA(r0);
            ACC(r0, u0);
        }
        int row = b * BROWS + rl;
        if (row < N) {
            float2 o;
            o.x = fmaxf(acc.x + bi.x, 0.f);
            o.y = fmaxf(acc.y + bi.y, 0.f);
            *(float2*)&out[row * 128 + 2 * lane] = o;
        }
    }
#undef GA
#undef ACC
}

extern "C" void kernel_launch(void* const* d_in, const int* in_sizes, int n_in,
                              void* d_out, int out_size, void* d_ws, size_t ws_size,
                              hipStream_t stream) {
    const float* x    = (const float*)d_in[0];
    const float* W0   = (const float*)d_in[1];
    const float* W1   = (const float*)d_in[2];
    const float* bias = (const float*)d_in[3];
    const float* ev0  = (const float*)d_in[4];
    const float* ev1  = (const float*)d_in[5];
    const int*   ei0  = (const int*)d_in[6];
    const int*   ei1  = (const int*)d_in[7];
    float* out = (float*)d_out;

    const int N = in_sizes[0] / 128;      // 50000
    const int E = in_sizes[4];            // 800000
    const int NBINS2 = NBUCK * 2;         // 3126

    // Workspace layout
    char* w = (char*)d_ws;
    unsigned short* pre = (unsigned short*)w;   w += (size_t)2 * PREROWS * 128 * 2;  // 33.5 MB
    unsigned short* wt0 = (unsigned short*)w;   w += (size_t)128 * 128 * 2;
    unsigned short* wt1 = (unsigned short*)w;   w += (size_t)128 * 128 * 2;
    int* cur = (int*)w;                         w += (size_t)NBINS2 * 4;
    int2* recs = (int2*)w;                      w += (size_t)NBINS2 * BCAP * 8;      // 17.6 MB

    // Phase 0: W -> bf16 transposed + zero cur (one 9-block dispatch)
    prep_kernel<<<9, 256, 0, stream>>>(W0, W1, wt0, wt1, cur, NBINS2);

    // Phase 1: fused MFMA GEMM (x converted once per block in LDS)
    gemm_fused_kernel<<<N / 16, 512, 0, stream>>>(x, wt0, wt1, pre, N);

    // Phase 2: LDS counting-sort fill (coalesced write-out)
    dim3 fgrid((E + FT6 - 1) / FT6, 2);
    fill6_kernel<<<fgrid, 512, 0, stream>>>(ei0, ei1, ev0, ev1, cur, recs, E);

    // Phase 3: bucket-sorted gather aggregation + bias + relu
    aggregate10_kernel<<<NBUCK, 256, 0, stream>>>(cur, recs, pre, bias, out, N);
}

// Round 3
// 210.708 us; speedup vs baseline: 1.0737x; 1.0737x over previous
//
#include <hip/hip_runtime.h>
#include <hip/hip_bf16.h>

// GCN layer: out = relu( A0 @ (X W0) + A1 @ (X W1) + bias )
// N=50000, D=128, E=800000 per adjacency, fp32 in/out, COO edges.
//
// R16 (this round):
//   prep        verbatim.
//   gemm64      NEW: 64-row tiles (782 blocks, was 3125x16-row). B-frags
//               loaded ONCE per wave (32 VGPR) and reused across 4 m-tiles;
//               16B int4 pre stores; identical MFMA math/rounding to R13.
//   fill6       verbatim R15 (so vs R15 the only middle-phase delta is gemm).
//   aggregate9  verbatim R13 revert. R15 occupancy test was NULL: grid is
//               1563 blocks ~= 6.1/CU, already co-resident at the 6-block
//               cap -> raising cap to 8 cannot add waves. Gather pinned at
//               ~177MB FETCH / 3.2TB/s across 5 structural variants now.
// NEVER fuse gemm+fill into one 70KB-LDS dispatch (R14: pair 57 -> 72us).
// NEVER use fp32 LDS atomics in the per-record loop (R4: 1234us, R9: 1216us).
// NOTE: dur_us carries ~85us of fixed overhead (R13/R14 algebra); judge
//       middle-phase changes by total delta with aggregate held constant.

#define BROWS 32                   // bucket = 32 dst rows
#define NBUCK 1563                 // ceil(50000/32)
#define NB2 2048                   // padded bin count
#define BCAP 704                   // records per (bucket,adj); mean 512, +8.5 sigma
#define ACAP (2 * BCAP)
#define FT6 4096                   // fill tile (edges per block) = 512 thr * 8
#define PREROWS 65536              // adj stride in unified pre

typedef __attribute__((ext_vector_type(8))) short bf16x8;
typedef __attribute__((ext_vector_type(4))) float f32x4;

__device__ inline unsigned short f2bf(float f) {
    union { float f; unsigned u; } v; v.f = f;
    unsigned r = v.u + 0x7fff + ((v.u >> 16) & 1);   // round-nearest-even
    return (unsigned short)(r >> 16);
}

// blocks 0..7: W transpose (4 k-slices x 2 Ws). block 8: zero cur.
__global__ __launch_bounds__(256) void prep_kernel(
    const float* __restrict__ W0, const float* __restrict__ W1,
    unsigned short* __restrict__ wt0, unsigned short* __restrict__ wt1,
    int* __restrict__ cur, int ncur)
{
    const int bid = blockIdx.x;
    const int tid = threadIdx.x;
    if (bid >= 8) {
        for (int i = tid; i < ncur; i += 256) cur[i] = 0;
        return;
    }
    const int which = bid >> 2;
    const int k0 = (bid & 3) * 32;
    const float* __restrict__ W = which ? W1 : W0;
    unsigned short* __restrict__ wt = which ? wt1 : wt0;
    for (int i = tid; i < 32 * 128; i += 256) {
        int k = k0 + (i >> 7), n = i & 127;
        wt[n * 128 + k] = f2bf(W[k * 128 + n]);
    }
}

// 64-row tile, BOTH adjacencies. Waves 0-3 -> W0 col-strips, 4-7 -> W1.
// B-frags (8 x bf16x8 = 32 VGPR) loaded once, reused across 4 m-tiles.
// A staged fp32->bf16 in LDS once per block. C staged via wave-private
// LDS tile -> 16B int4 global stores. 27.6 KB LDS -> 4 blocks/CU (wave cap).
__global__ __launch_bounds__(512) void gemm64_kernel(
    const float* __restrict__ x,
    const unsigned short* __restrict__ wt0,
    const unsigned short* __restrict__ wt1,
    unsigned short* __restrict__ pre,    // unified: adj*PREROWS + row
    int N)
{
    __shared__ unsigned short sA[64][136];  // bf16 A-tile (272B row = 17x16B)
    __shared__ short ctile[8][16][40];      // per-wave 16x32 C tile (+pad)

    const int tid = threadIdx.x;
    const int m0 = blockIdx.x * 64;

    // stage A: 64 rows x 32 float4; 4 float4 per thread, guarded (tail block)
#pragma unroll
    for (int t = 0; t < 4; ++t) {
        int idx = t * 512 + tid;
        int r = idx >> 5;                 // 0..63
        int c4 = (idx & 31) << 2;
        if (m0 + r < N) {
            float4 v = *(const float4*)&x[(size_t)(m0 + r) * 128 + c4];
            ushort4 s;
            s.x = f2bf(v.x); s.y = f2bf(v.y); s.z = f2bf(v.z); s.w = f2bf(v.w);
            *(ushort4*)&sA[r][c4] = s;
        }
    }

    const int w = tid >> 6;
    const int lane = tid & 63;
    const int adj = w >> 2;
    const int wq = w & 3;
    const unsigned short* __restrict__ wt = adj ? wt1 : wt0;
    unsigned short* __restrict__ po = pre + (size_t)adj * PREROWS * 128;
    const int l15 = lane & 15;
    const int quad = lane >> 4;
    const int nA = wq * 32 + l15;

    // B fragments: load once from global (32KB wt is L2-resident), reuse 4x
    bf16x8 b0[4], b1[4];
#pragma unroll
    for (int kk = 0; kk < 4; ++kk) {
        b0[kk] = *(const bf16x8*)&wt[nA * 128 + kk * 32 + quad * 8];
        b1[kk] = *(const bf16x8*)&wt[(nA + 16) * 128 + kk * 32 + quad * 8];
    }
    __syncthreads();

    const int rr = lane >> 2, cg = (lane & 3) * 8;
#pragma unroll
    for (int mt = 0; mt < 4; ++mt) {
        f32x4 c0 = {0.f, 0.f, 0.f, 0.f};
        f32x4 c1 = {0.f, 0.f, 0.f, 0.f};
#pragma unroll
        for (int kk = 0; kk < 4; ++kk) {
            union { bf16x8 v; ushort4 h[2]; } au;
            au.h[0] = *(const ushort4*)&sA[mt * 16 + l15][kk * 32 + quad * 8];
            au.h[1] = *(const ushort4*)&sA[mt * 16 + l15][kk * 32 + quad * 8 + 4];
            c0 = __builtin_amdgcn_mfma_f32_16x16x32_bf16(au.v, b0[kk], c0, 0, 0, 0);
            c1 = __builtin_amdgcn_mfma_f32_16x16x32_bf16(au.v, b1[kk], c1, 0, 0, 0);
        }
        // stage C into wave-private LDS tile (wave-internal dep: no barrier;
        // reuse across mt is safe -- same wave, in-order LDS)
#pragma unroll
        for (int i = 0; i < 4; ++i) {
            ctile[w][quad * 4 + i][l15]      = (short)f2bf(c0[i]);
            ctile[w][quad * 4 + i][16 + l15] = (short)f2bf(c1[i]);
        }
        int row = m0 + mt * 16 + rr;
        if (row < N) {
            int4 sv = *(const int4*)&ctile[w][rr][cg];   // 16B, aligned
            *(int4*)&po[(size_t)row * 128 + wq * 32 + cg] = sv;
        }
    }
}

// Standalone fill (verbatim R15): 512 thr / 4096 edges, wave-shuffle scan,
// int4/float4 edge loads, start[k] == lcur[k-1] trick. grid (196, 2);
// ~69.9 KB LDS -> 2 blocks/CU, 392 blocks cover all 256 CUs.
__global__ __launch_bounds__(512) void fill6_kernel(
    const int* __restrict__ ei0, const int* __restrict__ ei1,
    const float* __restrict__ ev0, const float* __restrict__ ev1,
    int* __restrict__ cur, int2* __restrict__ recs, int E)
{
    __shared__ int2 srt[FT6];                 // 32 KB sorted records
    __shared__ alignas(16) int lcnt[NB2];     // 8 KB per-bucket counts
    __shared__ alignas(16) int lcur[NB2];     // 8 KB cursors (end == next start)
    __shared__ unsigned short skey[FT6];      // 8 KB bucket of each sorted record
    __shared__ int gpos[NBUCK];               // 6.25 KB global base per bucket
    __shared__ int glim[NBUCK];               // 6.25 KB
    __shared__ int wsum[8];
    __shared__ int stotal;

    const int tid = threadIdx.x;
    const int a = blockIdx.y;
    const int e0 = blockIdx.x * FT6;
    const int* __restrict__ ei = a ? ei1 : ei0;
    const float* __restrict__ ev = a ? ev1 : ev0;

    ((int4*)lcnt)[tid] = make_int4(0, 0, 0, 0);
    __syncthreads();

    // load 8 consecutive edges per thread (int4/float4 vector loads)
    const int eb = e0 + tid * 8;
    int dd[8], ss[8]; float vv[8];
    if (e0 + FT6 <= E) {
        int4 d0 = *(const int4*)(ei + eb);
        int4 d1 = *(const int4*)(ei + eb + 4);
        int4 s0 = *(const int4*)(ei + E + eb);
        int4 s1 = *(const int4*)(ei + E + eb + 4);
        float4 v0 = *(const float4*)(ev + eb);
        float4 v1 = *(const float4*)(ev + eb + 4);
        dd[0] = d0.x; dd[1] = d0.y; dd[2] = d0.z; dd[3] = d0.w;
        dd[4] = d1.x; dd[5] = d1.y; dd[6] = d1.z; dd[7] = d1.w;
        ss[0] = s0.x; ss[1] = s0.y; ss[2] = s0.z; ss[3] = s0.w;
        ss[4] = s1.x; ss[5] = s1.y; ss[6] = s1.z; ss[7] = s1.w;
        vv[0] = v0.x; vv[1] = v0.y; vv[2] = v0.z; vv[3] = v0.w;
        vv[4] = v1.x; vv[5] = v1.y; vv[6] = v1.z; vv[7] = v1.w;
    } else {
#pragma unroll
        for (int j = 0; j < 8; ++j) {
            int e = eb + j;
            if (e < E) { dd[j] = ei[e]; ss[j] = ei[E + e]; vv[j] = ev[e]; }
        }
    }
    int key8[8]; int2 rec[8];
#pragma unroll
    for (int j = 0; j < 8; ++j) {
        if (eb + j < E) {
            key8[j] = dd[j] >> 5;
            rec[j] = make_int2(((dd[j] & 31) << 17) | (a << 16) | ss[j],
                               __float_as_int(vv[j]));
            atomicAdd(&lcnt[key8[j]], 1);
        } else key8[j] = -1;
    }
    __syncthreads();

    // wave-shuffle exclusive scan over 2048 bins (4 per thread)
    const int lane = tid & 63;
    const int wv = tid >> 6;
    int4 c4 = ((const int4*)lcnt)[tid];
    int cc[4] = { c4.x, c4.y, c4.z, c4.w };
    int tsum = cc[0] + cc[1] + cc[2] + cc[3];
    int p = tsum;
#pragma unroll
    for (int o = 1; o < 64; o <<= 1) {
        int t = __shfl_up(p, o);
        if (lane >= o) p += t;
    }
    if (lane == 63) wsum[wv] = p;
    __syncthreads();
    int wbase = 0;
#pragma unroll
    for (int w2 = 0; w2 < 7; ++w2) wbase += (w2 < wv) ? wsum[w2] : 0;
    if (tid == 511) stotal = wbase + p;
    int off = wbase + p - tsum;          // exclusive start of bin 4*tid
    const int k0 = 4 * tid;
#pragma unroll
    for (int h = 0; h < 4; ++h) {
        lcur[k0 + h] = off;
        if (k0 + h < NBUCK && cc[h] > 0) {
            int bin = (k0 + h) * 2 + a;
            int g = atomicAdd(&cur[bin], cc[h]);
            int lim = BCAP - g; if (lim < 0) lim = 0;   // overflow guard
            gpos[k0 + h] = bin * BCAP + g;
            glim[k0 + h] = lim;
        }
        off += cc[h];
    }
    __syncthreads();

    // scatter into LDS sorted by bucket
#pragma unroll
    for (int j = 0; j < 8; ++j) {
        if (key8[j] >= 0) {
            int pp = atomicAdd(&lcur[key8[j]], 1);
            srt[pp] = rec[j];
            skey[pp] = (unsigned short)key8[j];
        }
    }
    __syncthreads();

    // coalesced write-out; start[k] == lcur[k-1] (ends are next starts)
    const int total = stotal;
    for (int i = tid; i < total; i += 512) {
        int k = skey[i];
        int st = k ? lcur[k - 1] : 0;
        int r = i - st;
        if (r < glim[k]) recs[gpos[k] + r] = srt[i];
    }
}

// One block per 32-row bucket (256 thr = 4 waves, wave wv -> rows wv*8..+7).
// Stage records in LDS, counting-sort FULL records by row (32 keys), then
// 8x-unrolled independent gathers from the unified pre, register accumulate,
// fused bias+relu writeout. (Verbatim R11/R12/R13: measured 61-62.7us.)
__global__ __launch_bounds__(256, 6) void aggregate9_kernel(
    const int* __restrict__ cur, const int2* __restrict__ recs,
    const unsigned short* __restrict__ pre,
    const float* __restrict__ bias,
    float* __restrict__ out, int N)
{
    __shared__ int2 srec[ACAP];             // 11.3 KB staged raw
    __shared__ int2 srt[ACAP];              // 11.3 KB row-sorted
    __shared__ int lcnt[32];
    __shared__ int lstart[32];
    __shared__ int lcur[32];

    const int b = blockIdx.x;
    const int tid = threadIdx.x;

    int n0 = cur[2 * b];     if (n0 > BCAP) n0 = BCAP;
    int n1 = cur[2 * b + 1]; if (n1 > BCAP) n1 = BCAP;
    const int total = n0 + n1;
    const int base0 = (2 * b) * BCAP, base1 = (2 * b + 1) * BCAP;

    if (tid < 32) lcnt[tid] = 0;
    __syncthreads();

    // stage + per-row counts (int LDS atomics)
    for (int i = tid; i < total; i += 256) {
        int2 r = (i < n0) ? recs[base0 + i] : recs[base1 + i - n0];
        srec[i] = r;
        atomicAdd(&lcnt[(r.x >> 17) & 31], 1);
    }
    __syncthreads();

    // wave 0 lanes 0-31: shfl exclusive scan of 32 counters
    if (tid < 32) {
        int cme = lcnt[tid];
        int p = cme;
#pragma unroll
        for (int o = 1; o < 32; o <<= 1) {
            int t = __shfl_up(p, o);
            if (tid >= o) p += t;
        }
        lstart[tid] = p - cme;
        lcur[tid] = p - cme;
    }
    __syncthreads();

    // scatter full records sorted by row
    for (int i = tid; i < total; i += 256) {
        int2 r = srec[i];
        srt[atomicAdd(&lcur[(r.x >> 17) & 31], 1)] = r;
    }
    __syncthreads();

    // gather: wave wv owns rows wv*8 .. wv*8+7; both adjacencies in one run
    const int wv = tid >> 6;
    const int lane = tid & 63;
    const float2 bi = *(const float2*)&bias[lane * 2];

#define GA(r) (*(const unsigned*)&pre[((r).x & 0x1ffff) * 128 + 2 * lane])
#define ACC(r, u) { float v = __int_as_float((r).y);                    \
        acc.x = fmaf(v, __uint_as_float((u) << 16), acc.x);             \
        acc.y = fmaf(v, __uint_as_float((u) & 0xffff0000u), acc.y); }

    for (int t = 0; t < 8; ++t) {
        const int rl = wv * 8 + t;
        const int s = lstart[rl];
        const int e = s + lcnt[rl];
        float2 acc = make_float2(0.f, 0.f);
        int j = s;
        for (; j + 8 <= e; j += 8) {
            int2 r0 = srt[j], r1 = srt[j + 1], r2 = srt[j + 2], r3 = srt[j + 3];
            int2 r4 = srt[j + 4], r5 = srt[j + 5], r6 = srt[j + 6], r7 = srt[j + 7];
            unsigned u0 = GA(r0), u1 = GA(r1), u2 = GA(r2), u3 = GA(r3);
            unsigned u4 = GA(r4), u5 = GA(r5), u6 = GA(r6), u7 = GA(r7);
            ACC(r0, u0); ACC(r1, u1); ACC(r2, u2); ACC(r3, u3);
            ACC(r4, u4); ACC(r5, u5); ACC(r6, u6); ACC(r7, u7);
        }
        for (; j + 4 <= e; j += 4) {
            int2 r0 = srt[j], r1 = srt[j + 1], r2 = srt[j + 2], r3 = srt[j + 3];
            unsigned u0 = GA(r0), u1 = GA(r1), u2 = GA(r2), u3 = GA(r3);
            ACC(r0, u0); ACC(r1, u1); ACC(r2, u2); ACC(r3, u3);
        }
        for (; j < e; ++j) {
            int2 r0 = srt[j];
            unsigned u0 = GA(r0);
            ACC(r0, u0);
        }
        int row = b * BROWS + rl;
        if (row < N) {
            float2 o;
            o.x = fmaxf(acc.x + bi.x, 0.f);
            o.y = fmaxf(acc.y + bi.y, 0.f);
            *(float2*)&out[row * 128 + 2 * lane] = o;
        }
    }
#undef GA
#undef ACC
}

extern "C" void kernel_launch(void* const* d_in, const int* in_sizes, int n_in,
                              void* d_out, int out_size, void* d_ws, size_t ws_size,
                              hipStream_t stream) {
    const float* x    = (const float*)d_in[0];
    const float* W0   = (const float*)d_in[1];
    const float* W1   = (const float*)d_in[2];
    const float* bias = (const float*)d_in[3];
    const float* ev0  = (const float*)d_in[4];
    const float* ev1  = (const float*)d_in[5];
    const int*   ei0  = (const int*)d_in[6];
    const int*   ei1  = (const int*)d_in[7];
    float* out = (float*)d_out;

    const int N = in_sizes[0] / 128;      // 50000
    const int E = in_sizes[4];            // 800000
    const int NBINS2 = NBUCK * 2;         // 3126

    // Workspace layout
    char* w = (char*)d_ws;
    unsigned short* pre = (unsigned short*)w;   w += (size_t)2 * PREROWS * 128 * 2;  // 33.5 MB
    unsigned short* wt0 = (unsigned short*)w;   w += (size_t)128 * 128 * 2;
    unsigned short* wt1 = (unsigned short*)w;   w += (size_t)128 * 128 * 2;
    int* cur = (int*)w;                         w += (size_t)NBINS2 * 4;
    int2* recs = (int2*)w;                      w += (size_t)NBINS2 * BCAP * 8;      // 17.6 MB

    // Phase 0: W -> bf16 transposed + zero cur (one 9-block dispatch)
    prep_kernel<<<9, 256, 0, stream>>>(W0, W1, wt0, wt1, cur, NBINS2);

    // Phase 1: 64-row MFMA GEMM (B-frags in registers, reused across m-tiles)
    gemm64_kernel<<<(N + 63) / 64, 512, 0, stream>>>(x, wt0, wt1, pre, N);

    // Phase 2: LDS counting-sort fill (coalesced write-out)
    dim3 fgrid((E + FT6 - 1) / FT6, 2);
    fill6_kernel<<<fgrid, 512, 0, stream>>>(ei0, ei1, ev0, ev1, cur, recs, E);

    // Phase 3: bucket-sorted gather aggregation + bias + relu
    aggregate9_kernel<<<NBUCK, 256, 0, stream>>>(cur, recs, pre, bias, out, N);
}